// Round 12
// baseline (851.340 us; speedup 1.0000x reference)
//
#include <hip/hip_runtime.h>

// ---------------------------------------------------------------------------
// Grid attention v13, bf16 MFMA (gfx950). 4096 windows; n=49; D=512; 16h x 32.
// = v12 dataflow (709us) at 1024 threads / 16 waves = 4 waves/SIMD (2x occ):
//   4 quads x 4 waves; quad q owns heads q*4..q*4+3, ONE shared scratch/quad.
//   Proj split 2x2 (wave(m2,n2): rows m2*32..+32, cols n2*16..+16).
//   Attention split M 4-way (wave iw owns one 16-query i-tile end-to-end).
//   Swapped QK^T -> in-lane softmax (2 shfl), normalized P packed uint2.
// LDS = 141824: xb 50176 | yb 50176 | 4 quads x 10368 (qb 3136|kb 3136|vt 4096)
// ws (2.5MB): Wq/Wk/Wv pre-swizzled B-frags + biasT (sim^T layout).
// ---------------------------------------------------------------------------

typedef __bf16 bf16x8 __attribute__((ext_vector_type(8)));
typedef __attribute__((ext_vector_type(4))) float f32x4;

#define DEVI __device__ __forceinline__

DEVI unsigned short f2bf(float f) {  // round-to-nearest-even
  union { float f; unsigned u; } v; v.f = f;
  unsigned r = v.u + 0x7FFFu + ((v.u >> 16) & 1u);
  return (unsigned short)(r >> 16);
}
DEVI unsigned pkbf(float a, float b) {
  return (unsigned)f2bf(a) | ((unsigned)f2bf(b) << 16);
}

#define MFMA16(a, b, c) __builtin_amdgcn_mfma_f32_16x16x32_bf16((a), (b), (c), 0, 0, 0)

#define SWZ_Y(r)  ((((unsigned)(r)) & 7u) << 4)
#define SWZ_A(r)  (((((unsigned)(r)) >> 2) & 3u) << 5)
#define SWZ_P(r)  ((((unsigned)(r)) & 7u) << 4)
#define SWZ_VT(r) ((((unsigned)(r)) & 7u) << 4)

// ---------------- prep: weights -> swizzled bf16 frags, bias -> sim^T layout
__global__ void prep_kernel(const float* __restrict__ Wq, const float* __restrict__ Wkv,
                            const float* __restrict__ bt, char* __restrict__ ws) {
  int t = blockIdx.x * 256 + threadIdx.x;
  if (t < 786432) {  // 3 * 16 * 2 * 16 * 64 * 8 bf16 elements
    int e = t & 7, lane = (t >> 3) & 63, ks = (t >> 9) & 15, nt = (t >> 13) & 1,
        h = (t >> 14) & 15, T = t >> 18;
    int row = ks * 32 + (lane >> 4) * 8 + e;     // K index in [0,512)
    int col = h * 32 + nt * 16 + (lane & 15);    // N index
    float v;
    if (T == 0)      v = Wq[row * 512 + col] * 0.17677669529663687f;  // fold 1/sqrt(32)
    else if (T == 1) v = Wkv[row * 1024 + col];
    else             v = Wkv[row * 1024 + 512 + col];
    ((unsigned short*)ws)[t] = f2bf(v);
  }
  if (t < 262144) {  // 16h * 4 i-tile * 4 j-tile * 64 lane * 4 reg, sim^T layout
    int r = t & 3, lane = (t >> 2) & 63, jt = (t >> 8) & 3, it = (t >> 10) & 3,
        h = (t >> 12) & 15;
    int i = it * 16 + (lane & 15);               // query: lane&15 = col of sim^T
    int j = jt * 16 + ((lane >> 4) & 3) * 4 + r; // key: regs = rows of sim^T
    float v;
    if (j >= 49)      v = -1e30f;   // mask padded key slots
    else if (i >= 49) v = 0.0f;     // padded query cols: keep finite
    else {
      int hi = i / 7, wi = i % 7, hj = j / 7, wj = j % 7;
      v = bt[((hi - hj + 6) * 13 + (wi - wj + 6)) * 16 + h];
    }
    ((float*)(ws + 1572864))[t] = v;
  }
}

// ---------------- LDS fragment loaders --------------------------------------
DEVI bf16x8 ldXY(const char* base, int row, int kc) {
  unsigned a = ((unsigned)(row * 1024 + kc * 2)) ^ SWZ_Y(row);
  return *(const bf16x8*)(base + a);
}
DEVI bf16x8 ldXY_c(const char* base, int row, int kc) {
  int rc = row < 48 ? row : 48;
  bf16x8 v = ldXY(base, rc, kc);
  if (row > 48) {
    union { long long z[2]; bf16x8 v; } u; u.z[0] = 0; u.z[1] = 0;
    v = u.v;
  }
  return v;
}
DEVI bf16x8 ldQK(const char* base, int row, int kc) {
  int rc = row < 48 ? row : 48;
  unsigned a = ((unsigned)(rc * 64 + kc * 2)) ^ SWZ_A(rc);
  return *(const bf16x8*)(base + a);
}
DEVI bf16x8 ldP2(const char* base, int row, int jc) {
  int rc = row < 48 ? row : 48;
  unsigned a = ((unsigned)(rc * 128 + jc * 2)) ^ SWZ_P(rc);
  return *(const bf16x8*)(base + a);
}
DEVI bf16x8 ldVT(const char* base, int dh, int jc) {
  unsigned a = ((unsigned)(dh * 128 + jc * 2)) ^ SWZ_VT(dh);
  return *(const bf16x8*)(base + a);
}

// ---------------- main fused kernel ----------------------------------------
__global__ __launch_bounds__(1024, 4)
void attn_kernel(const float* __restrict__ x, const float* __restrict__ y,
                 const char* __restrict__ wsW, const float* __restrict__ biasD,
                 float* __restrict__ out) {
  extern __shared__ char smem[];
  char* xb = smem;            // 50176
  char* yb = smem + 50176;    // 50176
  const int tid = threadIdx.x;
  const int lane = tid & 63, wave = tid >> 6;
  const int quad = wave >> 2, m2 = (wave >> 1) & 1, n2 = wave & 1, iw = wave & 3;
  const int g = lane >> 4, lr = lane & 15;
  char* pbase = smem + 100352 + quad * 10368;  // per-QUAD scratch
  char* qb = pbase;             // 3136
  char* kb = pbase + 3136;      // 3136
  char* vt = pbase + 6272;      // 4096
  char* Pb = pbase;             // P aliases qb+kb (6272B) -- barrier-guarded

  const int bw = blockIdx.x;
  const float* xs = x + (size_t)bw * 25088;
  const float* ys = y + (size_t)bw * 25088;

  // ---- stage x,y windows to LDS as bf16 ----
  for (int it = tid; it < 6272; it += 1024) {
    float4 v = ((const float4*)xs)[it];
    float4 w = ((const float4*)ys)[it];
    int i = it >> 7;               // row 0..48
    int k = (it & 127) << 2;       // col 0..508
    unsigned a = ((unsigned)(i * 1024 + k * 2)) ^ SWZ_Y(i);
    uint2 ux, uy;
    ux.x = pkbf(v.x, v.y); ux.y = pkbf(v.z, v.w);
    uy.x = pkbf(w.x, w.y); uy.y = pkbf(w.z, w.w);
    *(uint2*)(xb + a) = ux;
    *(uint2*)(yb + a) = uy;
  }

  const bf16x8* wsQ = (const bf16x8*)wsW;
  const bf16x8* wsK = (const bf16x8*)(wsW + 524288);
  const bf16x8* wsV = (const bf16x8*)(wsW + 1048576);
  const f32x4* bD = (const f32x4*)biasD;
  const f32x4 fz = {0.f, 0.f, 0.f, 0.f};

  const int r0 = m2 * 32 + lr;        // A-frag row 0 (<=47, no clamp needed)
  const int r1 = m2 * 32 + 16 + lr;   // A-frag row 1 (48..63 when m2=1)

  for (int hi = 0; hi < 4; ++hi) {
    const int h = quad * 4 + hi;

    __syncthreads();  // quad scratch free (all attn reads of prev head done)

    // ---- Q-pass: rows m2*32..+32, cols n2*16..+16, 8-deep preload ----
    f32x4 accq[2];
    accq[0] = fz; accq[1] = fz;
    {
      const bf16x8* pQ = wsQ + (size_t)((h * 2 + n2) * 16) * 64 + lane;
      bf16x8 qsr[8];
      #pragma unroll
      for (int i = 0; i < 8; ++i) qsr[i] = pQ[i * 64];
      #pragma unroll
      for (int ks = 0; ks < 16; ++ks) {
        bf16x8 bq = qsr[ks & 7];
        if (ks < 8) qsr[ks & 7] = pQ[(ks + 8) * 64];
        int kc = ks * 32 + g * 8;
        bf16x8 a0 = ldXY(xb, r0, kc);
        bf16x8 a1 = ldXY_c(xb, r1, kc);
        accq[0] = MFMA16(a0, bq, accq[0]);
        accq[1] = MFMA16(a1, bq, accq[1]);
      }
    }
    // store q: [row][dh] u16 scatter
    #pragma unroll
    for (int mt = 0; mt < 2; ++mt)
      #pragma unroll
      for (int r = 0; r < 4; ++r) {
        int row = m2 * 32 + mt * 16 + g * 4 + r;
        if (row < 49) {
          unsigned a = ((unsigned)(row * 64 + (n2 * 16 + lr) * 2)) ^ SWZ_A(row);
          *(unsigned short*)(qb + a) = f2bf(accq[mt][r]);
        }
      }

    // ---- KV-pass: same split, rolling 8-deep dual preload ----
    f32x4 acck[2], accv[2];
    acck[0] = fz; acck[1] = fz; accv[0] = fz; accv[1] = fz;
    {
      const bf16x8* pK = wsK + (size_t)((h * 2 + n2) * 16) * 64 + lane;
      const bf16x8* pV = wsV + (size_t)((h * 2 + n2) * 16) * 64 + lane;
      bf16x8 ksr[8], vsr[8];
      #pragma unroll
      for (int i = 0; i < 8; ++i) { ksr[i] = pK[i * 64]; vsr[i] = pV[i * 64]; }
      #pragma unroll
      for (int ks = 0; ks < 16; ++ks) {
        bf16x8 bk = ksr[ks & 7], bv = vsr[ks & 7];
        if (ks < 8) {
          ksr[ks & 7] = pK[(ks + 8) * 64];
          vsr[ks & 7] = pV[(ks + 8) * 64];
        }
        int kc = ks * 32 + g * 8;
        bf16x8 a0 = ldXY(yb, r0, kc);
        bf16x8 a1 = ldXY_c(yb, r1, kc);
        acck[0] = MFMA16(a0, bk, acck[0]);
        acck[1] = MFMA16(a1, bk, acck[1]);
        accv[0] = MFMA16(a0, bv, accv[0]);
        accv[1] = MFMA16(a1, bv, accv[1]);
      }
    }
    // store k (scatter u16) and vt (ALL toks of this wave's rows, finite)
    #pragma unroll
    for (int mt = 0; mt < 2; ++mt) {
      #pragma unroll
      for (int r = 0; r < 4; ++r) {
        int row = m2 * 32 + mt * 16 + g * 4 + r;
        if (row < 49) {
          unsigned a = ((unsigned)(row * 64 + (n2 * 16 + lr) * 2)) ^ SWZ_A(row);
          *(unsigned short*)(kb + a) = f2bf(acck[mt][r]);
        }
      }
      int dh = n2 * 16 + lr;
      int t0 = m2 * 32 + mt * 16 + g * 4;
      unsigned a = ((unsigned)(dh * 128 + t0 * 2)) ^ SWZ_VT(dh);
      uint2 pk;
      pk.x = pkbf(accv[mt][0], accv[mt][1]);
      pk.y = pkbf(accv[mt][2], accv[mt][3]);
      *(uint2*)(vt + a) = pk;
    }

    __syncthreads();  // q,k,vt visible to all quad waves

    // ======== attention: wave owns i-tile iw (16 queries) ========
    f32x4 bias[4];
    #pragma unroll
    for (int jt = 0; jt < 4; ++jt)
      bias[jt] = bD[(size_t)(((h * 4 + iw) * 4 + jt) * 64 + lane)];

    bf16x8 qa = ldQK(qb, iw * 16 + lr, g * 8);
    bf16x8 kf[4];
    #pragma unroll
    for (int jt = 0; jt < 4; ++jt) kf[jt] = ldQK(kb, jt * 16 + lr, g * 8);

    // sim^T: col = query i (lane&15), regs = key j
    f32x4 vals[4];
    #pragma unroll
    for (int jt = 0; jt < 4; ++jt) vals[jt] = MFMA16(kf[jt], qa, fz);
    #pragma unroll
    for (int jt = 0; jt < 4; ++jt) vals[jt] = vals[jt] + bias[jt];

    // in-lane softmax (16 j-values/lane) + 2 shfl across g-replicas; normalize
    uint2 pks[4];
    {
      float m = vals[0][0];
      #pragma unroll
      for (int jt = 0; jt < 4; ++jt)
        #pragma unroll
        for (int r = 0; r < 4; ++r) m = fmaxf(m, vals[jt][r]);
      m = fmaxf(m, __shfl_xor(m, 16));
      m = fmaxf(m, __shfl_xor(m, 32));
      float s = 0.f;
      #pragma unroll
      for (int jt = 0; jt < 4; ++jt)
        #pragma unroll
        for (int r = 0; r < 4; ++r) {
          float pv = __expf(vals[jt][r] - m);
          vals[jt][r] = pv;
          s += pv;
        }
      s += __shfl_xor(s, 16);
      s += __shfl_xor(s, 32);
      float inv = 1.0f / s;
      #pragma unroll
      for (int jt = 0; jt < 4; ++jt) {
        pks[jt].x = pkbf(vals[jt][0] * inv, vals[jt][1] * inv);
        pks[jt].y = pkbf(vals[jt][2] * inv, vals[jt][3] * inv);
      }
    }

    __syncthreads();  // all quad waves done reading q/k -> P may overwrite

    // P write: packed uint2, own query rows, conflict-free
    {
      int i = iw * 16 + lr;
      if (i < 49) {
        #pragma unroll
        for (int jt = 0; jt < 4; ++jt) {
          unsigned a = ((unsigned)(i * 128 + (jt * 16 + g * 4) * 2)) ^ SWZ_P(i);
          *(uint2*)(Pb + a) = pks[jt];
        }
      }
    }

    // PV: out^T[dh][i] = V^T @ P^T ; A = vt rows (quad-shared), B = own P rows
    f32x4 acco[2];
    acco[0] = fz; acco[1] = fz;
    #pragma unroll
    for (int ks = 0; ks < 2; ++ks) {
      int jc = ks * 32 + g * 8;
      bf16x8 av0 = ldVT(vt, lr, jc);
      bf16x8 av1 = ldVT(vt, lr + 16, jc);
      bf16x8 bp = ldP2(Pb, iw * 16 + lr, jc);
      acco[0] = MFMA16(av0, bp, acco[0]);
      acco[1] = MFMA16(av1, bp, acco[1]);
    }

    // store (already normalized): tok = col (lane&15), dh rows f32x4
    float* ow = out + (size_t)bw * 25088 + h * 32;
    {
      int tok = iw * 16 + lr;
      if (tok < 49) {
        #pragma unroll
        for (int md = 0; md < 2; ++md)
          *(f32x4*)(&ow[(size_t)tok * 512 + md * 16 + g * 4]) = acco[md];
      }
    }
  }
}

extern "C" void kernel_launch(void* const* d_in, const int* in_sizes, int n_in,
                              void* d_out, int out_size, void* d_ws, size_t ws_size,
                              hipStream_t stream) {
  (void)in_sizes; (void)n_in; (void)out_size; (void)ws_size;
  const float* x = (const float*)d_in[0];
  const float* y = (const float*)d_in[1];
  const float* Wq = (const float*)d_in[2];
  const float* Wkv = (const float*)d_in[3];
  const float* bt = (const float*)d_in[4];
  float* out = (float*)d_out;
  char* ws = (char*)d_ws;

  prep_kernel<<<3072, 256, 0, stream>>>(Wq, Wkv, bt, ws);

  (void)hipFuncSetAttribute((const void*)attn_kernel,
                            hipFuncAttributeMaxDynamicSharedMemorySize, 141824);
  attn_kernel<<<4096, 1024, 141824, stream>>>(x, y, (const char*)ws,
                                              (const float*)(ws + 1572864), out);
}

// Round 14
// 848.084 us; speedup vs baseline: 1.0038x; 1.0038x over previous
//
#include <hip/hip_runtime.h>

// ---------------------------------------------------------------------------
// Grid attention v15, bf16 MFMA 32x32x16 (gfx950). 4096 windows; n=49; D=512.
// = v14 (all matmuls on mfma_f32_32x32x16_bf16, M-split proj, swapped QK,
//   in-lane softmax) with the bias-table bug fixed: bias now carries the
//   query-block dim [16h][2it][2jt][64lane][16reg], i = it*32 + (lane&31);
//   kernel reads with it = sub. (v14 baked only i = lane&31 -> queries 32..48
//   got the wrong bias -> absmax 0.105.)
// C-layout (m74/m101): col=lane&31, row=(reg&3)+8*(reg>>2)+4*(lane>>5).
// LDS = 141824: xb 50176 | yb 50176 | 4 pairs x 10368 (qb 3136|kb 3136|vt 4096)
// ws: W-frags [3][16h][32ks][64lane][8e] bf16 (1.5MB) + bias 512KB @1572864.
// ---------------------------------------------------------------------------

typedef __bf16 bf16x8 __attribute__((ext_vector_type(8)));
typedef __attribute__((ext_vector_type(4))) float f32x4;
typedef __attribute__((ext_vector_type(16))) float f32x16;

#define DEVI __device__ __forceinline__

DEVI unsigned short f2bf(float f) {  // round-to-nearest-even
  union { float f; unsigned u; } v; v.f = f;
  unsigned r = v.u + 0x7FFFu + ((v.u >> 16) & 1u);
  return (unsigned short)(r >> 16);
}
DEVI unsigned pkbf(float a, float b) {
  return (unsigned)f2bf(a) | ((unsigned)f2bf(b) << 16);
}

#define MFMA32(a, b, c) __builtin_amdgcn_mfma_f32_32x32x16_bf16((a), (b), (c), 0, 0, 0)

#define SWZ_Y(r)  ((((unsigned)(r)) & 7u) << 4)
#define SWZ_A(r)  (((((unsigned)(r)) >> 2) & 3u) << 5)
#define SWZ_P(r)  ((((unsigned)(r)) & 7u) << 4)
#define SWZ_VT(r) ((((unsigned)(r)) & 7u) << 4)

// ---------------- prep: weights -> 32x32x16 B-frags, bias -> sim^T layout ---
__global__ void prep_kernel(const float* __restrict__ Wq, const float* __restrict__ Wkv,
                            const float* __restrict__ bt, char* __restrict__ ws) {
  int t = blockIdx.x * 256 + threadIdx.x;
  if (t < 786432) {  // 3 * 16h * 32ks * 64lane * 8e
    int e = t & 7, lane = (t >> 3) & 63, ks = (t >> 9) & 31,
        h = (t >> 14) & 15, T = t >> 18;
    int row = ks * 16 + (lane >> 5) * 8 + e;   // K index in [0,512)
    int col = h * 32 + (lane & 31);            // N index (dh)
    float v;
    if (T == 0)      v = Wq[row * 512 + col] * 0.17677669529663687f;  // fold 1/sqrt(32)
    else if (T == 1) v = Wkv[row * 1024 + col];
    else             v = Wkv[row * 1024 + 512 + col];
    ((unsigned short*)ws)[t] = f2bf(v);
  }
  if (t < 65536) {  // 16h * 2it * 2jt * 64lane * 16reg f32, sim^T 32x32 C-layout
    int reg = t & 15, lane = (t >> 4) & 63, jt = (t >> 10) & 1, it = (t >> 11) & 1,
        h = (t >> 12) & 15;
    int i = it * 32 + (lane & 31);                                   // query col
    int j = jt * 32 + (reg & 3) + 8 * (reg >> 2) + 4 * (lane >> 5);  // key row
    float v;
    if (j >= 49)      v = -1e30f;   // mask padded key slots
    else if (i >= 49) v = 0.0f;     // padded query cols: keep finite
    else {
      int hi2 = i / 7, wi = i % 7, hj = j / 7, wj = j % 7;
      v = bt[((hi2 - hj + 6) * 13 + (wi - wj + 6)) * 16 + h];
    }
    ((float*)(ws + 1572864))[t] = v;
  }
}

// ---------------- LDS fragment loaders --------------------------------------
DEVI bf16x8 ldXY(const char* base, int row, int kc) {  // xb/yb [49][512]
  unsigned a = ((unsigned)(row * 1024 + kc * 2)) ^ SWZ_Y(row);
  return *(const bf16x8*)(base + a);
}
DEVI bf16x8 ldQK(const char* base, int row, int kc) {  // qb/kb [49][32]
  int rc = row < 48 ? row : 48;
  unsigned a = ((unsigned)(rc * 64 + kc * 2)) ^ SWZ_A(rc);
  return *(const bf16x8*)(base + a);
}
DEVI bf16x8 ldP2(const char* base, int row, int jc) {  // P [49][64]
  int rc = row < 48 ? row : 48;
  unsigned a = ((unsigned)(rc * 128 + jc * 2)) ^ SWZ_P(rc);
  return *(const bf16x8*)(base + a);
}
DEVI bf16x8 ldVT(const char* base, int dh, int jc) {   // vt [32][64]
  unsigned a = ((unsigned)(dh * 128 + jc * 2)) ^ SWZ_VT(dh);
  return *(const bf16x8*)(base + a);
}

// ---------------- main fused kernel ----------------------------------------
__global__ __launch_bounds__(512, 2)
void attn_kernel(const float* __restrict__ x, const float* __restrict__ y,
                 const char* __restrict__ wsW, const float* __restrict__ biasD,
                 float* __restrict__ out) {
  extern __shared__ char smem[];
  char* xb = smem;            // 50176
  char* yb = smem + 50176;    // 50176
  const int tid = threadIdx.x;
  const int lane = tid & 63, wave = tid >> 6;
  const int p = wave >> 1, sub = wave & 1;
  const int il = lane & 31, hi = lane >> 5;
  char* pbase = smem + 100352 + p * 10368;  // per-PAIR scratch
  char* qb = pbase;             // 3136
  char* kb = pbase + 3136;      // 3136
  char* vt = pbase + 6272;      // 4096
  char* Pb = pbase;             // P aliases qb+kb (6272B) -- barrier-guarded

  const int bw = blockIdx.x;
  const float* xs = x + (size_t)bw * 25088;
  const float* ys = y + (size_t)bw * 25088;

  // ---- stage x,y windows to LDS as bf16 ----
  for (int it = tid; it < 6272; it += 512) {
    float4 v = ((const float4*)xs)[it];
    float4 w = ((const float4*)ys)[it];
    int i = it >> 7;               // row 0..48
    int k = (it & 127) << 2;       // col 0..508
    unsigned a = ((unsigned)(i * 1024 + k * 2)) ^ SWZ_Y(i);
    uint2 ux, uy;
    ux.x = pkbf(v.x, v.y); ux.y = pkbf(v.z, v.w);
    uy.x = pkbf(w.x, w.y); uy.y = pkbf(w.z, w.w);
    *(uint2*)(xb + a) = ux;
    *(uint2*)(yb + a) = uy;
  }

  const bf16x8* wsQ = (const bf16x8*)wsW;                  // [h][ks][lane]
  const bf16x8* wsK = (const bf16x8*)(wsW + 524288);
  const bf16x8* wsV = (const bf16x8*)(wsW + 1048576);
  const float* bD = (const float*)biasD;                   // [h][it][jt][lane][16]
  const f32x16 fz16 = {0,0,0,0, 0,0,0,0, 0,0,0,0, 0,0,0,0};

  // A-frag token row for projections (M-split): wave sub owns rows sub*32..+31
  int arow = sub * 32 + il; if (arow > 48) arow = 48;      // clamp padding
  const int kfb = hi * 8;                                  // k-frag base

  for (int hh = 0; hh < 4; ++hh) {
    const int h = p * 4 + hh;

    __syncthreads();  // scratch free: partner's attn reads of prev head done

    // ---- Q-pass (32x32x16): rows sub*32..+31 x dh 0..31, K=512 ----
    f32x16 aq = fz16;
    {
      const bf16x8* pQ = wsQ + (size_t)(h * 32) * 64 + lane;
      bf16x8 qsr[8];
      #pragma unroll
      for (int i = 0; i < 8; ++i) qsr[i] = pQ[i * 64];
      #pragma unroll
      for (int ks = 0; ks < 32; ++ks) {
        bf16x8 bq = qsr[ks & 7];
        if (ks < 24) qsr[ks & 7] = pQ[(ks + 8) * 64];
        bf16x8 af = ldXY(xb, arow, ks * 16 + kfb);
        aq = MFMA32(af, bq, aq);
      }
    }
    // store q: [row][dh] u16 scatter; row = sub*32 + rq*8 + hi*4 + r2
    #pragma unroll
    for (int rq = 0; rq < 4; ++rq)
      #pragma unroll
      for (int r2 = 0; r2 < 4; ++r2) {
        int row = sub * 32 + rq * 8 + hi * 4 + r2;
        if (row < 49) {
          unsigned a = ((unsigned)(row * 64 + il * 2)) ^ SWZ_A(row);
          *(unsigned short*)(qb + a) = f2bf(aq[rq * 4 + r2]);
        }
      }

    // ---- KV-pass (32x32x16): same rows, K and V share A-frags ----
    f32x16 ak = fz16, av = fz16;
    {
      const bf16x8* pK = wsK + (size_t)(h * 32) * 64 + lane;
      const bf16x8* pV = wsV + (size_t)(h * 32) * 64 + lane;
      bf16x8 ksr[8], vsr[8];
      #pragma unroll
      for (int i = 0; i < 8; ++i) { ksr[i] = pK[i * 64]; vsr[i] = pV[i * 64]; }
      #pragma unroll
      for (int ks = 0; ks < 32; ++ks) {
        bf16x8 bk = ksr[ks & 7], bv = vsr[ks & 7];
        if (ks < 24) {
          ksr[ks & 7] = pK[(ks + 8) * 64];
          vsr[ks & 7] = pV[(ks + 8) * 64];
        }
        bf16x8 af = ldXY(yb, arow, ks * 16 + kfb);
        ak = MFMA32(af, bk, ak);
        av = MFMA32(af, bv, av);
      }
    }
    // store k (u16 scatter) and vt ([dh][tok], packed uint2)
    #pragma unroll
    for (int rq = 0; rq < 4; ++rq) {
      #pragma unroll
      for (int r2 = 0; r2 < 4; ++r2) {
        int row = sub * 32 + rq * 8 + hi * 4 + r2;
        if (row < 49) {
          unsigned a = ((unsigned)(row * 64 + il * 2)) ^ SWZ_A(row);
          *(unsigned short*)(kb + a) = f2bf(ak[rq * 4 + r2]);
        }
      }
      int t0 = sub * 32 + rq * 8 + hi * 4;
      unsigned a = ((unsigned)(il * 128 + t0 * 2)) ^ SWZ_VT(il);
      uint2 pk;
      pk.x = pkbf(av[rq * 4 + 0], av[rq * 4 + 1]);
      pk.y = pkbf(av[rq * 4 + 2], av[rq * 4 + 3]);
      *(uint2*)(vt + a) = pk;
    }

    __syncthreads();  // q,k,vt visible to both waves of the pair

    // ======== attention (swapped QK^T, 32x32 tiles) ========
    // bias: [h][it=sub][jt][lane][16] -> 2x f32x16 via f32x4 loads
    f32x16 bias[2];
    #pragma unroll
    for (int jt = 0; jt < 2; ++jt) {
      const f32x4* bp = (const f32x4*)(bD + ((size_t)(((h * 2 + sub) * 2 + jt) * 64 + lane)) * 16);
      #pragma unroll
      for (int q4 = 0; q4 < 4; ++q4) {
        f32x4 b4 = bp[q4];
        bias[jt][q4 * 4 + 0] = b4[0]; bias[jt][q4 * 4 + 1] = b4[1];
        bias[jt][q4 * 4 + 2] = b4[2]; bias[jt][q4 * 4 + 3] = b4[3];
      }
    }

    // sim^T[j][i] = MFMA(A=k[j][dh], B=q[i][dh]); i = sub*32 + il
    bf16x8 bq0 = ldQK(qb, sub * 32 + il, kfb);        // dh 0..15 slice
    bf16x8 bq1 = ldQK(qb, sub * 32 + il, 16 + kfb);   // dh 16..31 slice
    f32x16 sim[2];
    #pragma unroll
    for (int jt = 0; jt < 2; ++jt) {
      bf16x8 ak0 = ldQK(kb, jt * 32 + il, kfb);
      bf16x8 ak1 = ldQK(kb, jt * 32 + il, 16 + kfb);
      f32x16 s = MFMA32(ak0, bq0, fz16);
      sim[jt] = MFMA32(ak1, bq1, s);
    }

    // in-lane softmax (32 j/lane) + 1 shfl_xor(32); normalize; pack P
    uint2 pks[2][4];
    {
      f32x16 vals[2];
      #pragma unroll
      for (int jt = 0; jt < 2; ++jt)
        #pragma unroll
        for (int r = 0; r < 16; ++r) vals[jt][r] = sim[jt][r] + bias[jt][r];
      float m = vals[0][0];
      #pragma unroll
      for (int jt = 0; jt < 2; ++jt)
        #pragma unroll
        for (int r = 0; r < 16; ++r) m = fmaxf(m, vals[jt][r]);
      m = fmaxf(m, __shfl_xor(m, 32));
      float s = 0.f;
      #pragma unroll
      for (int jt = 0; jt < 2; ++jt)
        #pragma unroll
        for (int r = 0; r < 16; ++r) {
          float pv = __expf(vals[jt][r] - m);
          vals[jt][r] = pv;
          s += pv;
        }
      s += __shfl_xor(s, 32);
      float inv = 1.0f / s;
      #pragma unroll
      for (int jt = 0; jt < 2; ++jt)
        #pragma unroll
        for (int rq = 0; rq < 4; ++rq) {
          pks[jt][rq].x = pkbf(vals[jt][rq * 4 + 0] * inv, vals[jt][rq * 4 + 1] * inv);
          pks[jt][rq].y = pkbf(vals[jt][rq * 4 + 2] * inv, vals[jt][rq * 4 + 3] * inv);
        }
    }

    __syncthreads();  // both waves done reading q/k -> P may overwrite alias

    // P write: row i = sub*32+il, j0 = jt*32 + rq*8 + hi*4, packed uint2
    {
      int i = sub * 32 + il;
      if (i < 49) {
        #pragma unroll
        for (int jt = 0; jt < 2; ++jt)
          #pragma unroll
          for (int rq = 0; rq < 4; ++rq) {
            int j0 = jt * 32 + rq * 8 + hi * 4;
            unsigned a = ((unsigned)(i * 128 + j0 * 2)) ^ SWZ_P(i);
            *(uint2*)(Pb + a) = pks[jt][rq];
          }
      }
    }

    // PV (32x32x16 swapped): out^T[dh][i]; A = vt[dh=il][j], B = P[i][j], K=j
    f32x16 oacc = fz16;
    #pragma unroll
    for (int ks = 0; ks < 4; ++ks) {
      int jc = ks * 16 + kfb;
      bf16x8 afv = ldVT(vt, il, jc);
      bf16x8 bfp = ldP2(Pb, sub * 32 + il, jc);
      oacc = MFMA32(afv, bfp, oacc);
    }

    // store: tok = col = sub*32+il; dh = rq*8 + hi*4 (+0..3) -> f32x4
    float* ow = out + (size_t)bw * 25088 + h * 32;
    {
      int tok = sub * 32 + il;
      if (tok < 49) {
        #pragma unroll
        for (int rq = 0; rq < 4; ++rq) {
          int dh0 = rq * 8 + hi * 4;
          f32x4 vv;
          vv[0] = oacc[rq * 4 + 0]; vv[1] = oacc[rq * 4 + 1];
          vv[2] = oacc[rq * 4 + 2]; vv[3] = oacc[rq * 4 + 3];
          *(f32x4*)(&ow[(size_t)tok * 512 + dh0]) = vv;
        }
      }
    }
  }
}

extern "C" void kernel_launch(void* const* d_in, const int* in_sizes, int n_in,
                              void* d_out, int out_size, void* d_ws, size_t ws_size,
                              hipStream_t stream) {
  (void)in_sizes; (void)n_in; (void)out_size; (void)ws_size;
  const float* x = (const float*)d_in[0];
  const float* y = (const float*)d_in[1];
  const float* Wq = (const float*)d_in[2];
  const float* Wkv = (const float*)d_in[3];
  const float* bt = (const float*)d_in[4];
  float* out = (float*)d_out;
  char* ws = (char*)d_ws;

  prep_kernel<<<3072, 256, 0, stream>>>(Wq, Wkv, bt, ws);

  (void)hipFuncSetAttribute((const void*)attn_kernel,
                            hipFuncAttributeMaxDynamicSharedMemorySize, 141824);
  attn_kernel<<<4096, 512, 141824, stream>>>(x, y, (const char*)ws,
                                             (const float*)(ws + 1572864), out);
}